// Round 7
// baseline (733.787 us; speedup 1.0000x reference)
//
#include <hip/hip_runtime.h>
#include <hip/hip_bf16.h>

// Problem constants
#define BROWS 16384
#define INDIM 4096
#define HID   2048
#define BOT   64
#define NC    8192

typedef __hip_bfloat16 bf16;
typedef __attribute__((ext_vector_type(8))) short bf16x8;
typedef __attribute__((ext_vector_type(4))) float f32x4;

#define MB (1048576L)

// ===========================================================================
// 256x256-tile 8-wave bf16 MFMA GEMM, m201-style 4-phase/K-tile schedule (v3).
// C = [relu](A @ B^T + bias). A: M x K row-major bf16; B: N x K row-major
// (transposed operand). BK=64. 512 threads = 8 waves (2M x 4N); per-wave
// output 128x64 = 8x4 frags of 16x16. LDS = 2 buf x (A 32KB + B 32KB).
// XOR chunk swizzle (16B chunk ^ row&7), proven 0-conflict.
//
// Phases per K-tile t (buf c=t&1): quadrants of the 8x4 frag grid.
//   ph1: read A mi0-3 (8) + B ni01 (4) = 12 ds_read; stage A-half0(t+1)
//        -> buf[c^1] (idle: its A last read at t-1 ph3, 2+ barriers ago)
//   ph2: read B ni23 (4); stage A-half1(t+1); MFMA mi0-3 x ni23
//   ph3: read A mi4-7 (8); stage B-half0(t+2) -> buf[c] B-region (B of
//        tile t fully consumed at ph2's lgkmcnt(0)); MFMA mi4-7 x ni01
//   ph4: 0 reads; stage B-half1(t+2); MFMA mi4-7 x ni23; vmcnt(4)
// Each phase: {reads, 1 half-tile stage (2 gloads), barrier, lgkmcnt(0),
// sched_barrier, setprio(1), 16 MFMA, setprio(0), barrier}.
// vmcnt(4) at ph4 drains A(t+1)+B(t+1) (8 oldest), keeps B(t+2) in flight
// (counted vmcnt, never 0 in steady state). Stage leads 3-7 phases >> HBM
// latency. Per-acc accumulation order (s0 then s1) identical to prior
// rounds -> bit-identical output.
// ===========================================================================
__device__ __forceinline__ void ldA(const short* aB, int wr, int hi, int lo,
                                    int m0, bf16x8 (&a)[4][2]) {
#pragma unroll
  for (int mi = 0; mi < 4; mi++) {
    const int p = wr * 128 + (m0 + mi) * 16 + lo;
#pragma unroll
    for (int s = 0; s < 2; s++) {
      const int ch = (s * 4 + hi) ^ (p & 7);
      a[mi][s] = *(const bf16x8*)(aB + p * 64 + ch * 8);
    }
  }
}

__device__ __forceinline__ void ldB(const short* bB, int wc, int hi, int lo,
                                    int n0, bf16x8 (&b)[2][2]) {
#pragma unroll
  for (int ni = 0; ni < 2; ni++) {
    const int q = wc * 64 + (n0 + ni) * 16 + lo;
#pragma unroll
    for (int s = 0; s < 2; s++) {
      const int ch = (s * 4 + hi) ^ (q & 7);
      b[ni][s] = *(const bf16x8*)(bB + q * 64 + ch * 8);
    }
  }
}

__device__ __forceinline__ void mm16(f32x4 (&acc)[8][4], int m0, int n0,
                                     const bf16x8 (&a)[4][2],
                                     const bf16x8 (&b)[2][2]) {
#pragma unroll
  for (int s = 0; s < 2; s++)
#pragma unroll
    for (int ni = 0; ni < 2; ni++)
#pragma unroll
      for (int mi = 0; mi < 4; mi++)
        acc[m0 + mi][n0 + ni] = __builtin_amdgcn_mfma_f32_16x16x32_bf16(
            a[mi][s], b[ni][s], acc[m0 + mi][n0 + ni], 0, 0, 0);
}

template <bool RELU, bool WF32, bool WB16>
__global__ __launch_bounds__(512, 2) void gemm256(
    const ushort* __restrict__ A, const ushort* __restrict__ B,
    const float* __restrict__ bias, float* __restrict__ Cf,
    ushort* __restrict__ Cb, int M, int N, int K) {
  __shared__ __align__(16) short sm[65536];  // 128 KB

  const int tid = threadIdx.x;
  const int lane = tid & 63;
  const int w = tid >> 6;             // 0..7
  const int wr = w >> 2, wc = w & 3;  // 2 x 4 wave grid
  const int hi = lane >> 4, lo = lane & 15;

  // XCD-aware bijective swizzle (grids here are %8==0)
  const int nwg = gridDim.x * gridDim.y;
  int bid = blockIdx.y * gridDim.x + blockIdx.x;
  if ((nwg & 7) == 0) bid = (bid & 7) * (nwg >> 3) + (bid >> 3);
  const int bx = bid % gridDim.x, by = bid / gridDim.x;
  const int m0 = by * 256, n0 = bx * 256;

  const ushort* Ag = A + (size_t)m0 * K;
  const ushort* Bg = B + (size_t)n0 * K;

  f32x4 acc[8][4] = {};

  // stage half h (tile rows h*128 .. h*128+127) of a 256x64 tile at K-offset
  // kelem into LDS short-offset dstShort. 2 gloads/thread; linear dest,
  // inverse-swizzled source (chunk kc = (j&7) ^ (row&7)).
  auto STAGEH = [&](const ushort* G, int kelem, int dstShort, int h) {
#pragma unroll
    for (int i = 0; i < 2; i++) {
      const int cc = i * 512 + tid;   // chunk in half: 0..1023
      const int r2 = cc >> 3;        // row in half 0..127
      const int r = h * 128 + r2;    // tile row
      const int kc = (cc & 7) ^ (r & 7);
      const ushort* src = G + (size_t)r * K + kelem + kc * 8;
      uint32_t m0v = __builtin_amdgcn_readfirstlane(
          (uint32_t)(uintptr_t)(sm + dstShort + h * 8192 +
                                (i * 512 + w * 64) * 8));
      asm volatile("s_mov_b32 m0, %0\n\t"
                   "global_load_lds_dwordx4 %1, off\n\t"
                   :: "s"(m0v), "v"(src) : "memory");
    }
  };

  const int nt = K / 64;  // >= 32 for all call sites

  // prologue: tile0 fully (A0,A1,B0,B1) + tile1's B halves (steady pattern).
  STAGEH(Ag, 0, 0, 0);
  STAGEH(Ag, 0, 0, 1);
  STAGEH(Bg, 0, 16384, 0);
  STAGEH(Bg, 0, 16384, 1);
  if (nt > 1) {
    STAGEH(Bg, 64, 32768 + 16384, 0);
    STAGEH(Bg, 64, 32768 + 16384, 1);
  }
  asm volatile("s_waitcnt vmcnt(4)" ::: "memory");  // tile0 landed; B(1) flies
  __builtin_amdgcn_s_barrier();

  for (int t = 0; t < nt; t++) {
    const int c = t & 1;
    const int aB = c * 32768, bB = aB + 16384;
    const int aN = (c ^ 1) * 32768;  // next tile's A region
    bf16x8 a[4][2], b01[2][2], b23[2][2];

    // ---- phase 1: A mi0-3 + B ni01 (12 reads); stage A-half0(t+1) ----
    ldA(sm + aB, wr, hi, lo, 0, a);
    ldB(sm + bB, wc, hi, lo, 0, b01);
    if (t + 1 < nt) STAGEH(Ag, (t + 1) * 64, aN, 0);
    asm volatile("s_waitcnt lgkmcnt(8)" ::: "memory");
    __builtin_amdgcn_s_barrier();
    asm volatile("s_waitcnt lgkmcnt(0)" ::: "memory");
    __builtin_amdgcn_sched_barrier(0);
    __builtin_amdgcn_s_setprio(1);
    mm16(acc, 0, 0, a, b01);
    __builtin_amdgcn_s_setprio(0);
    __builtin_amdgcn_s_barrier();

    // ---- phase 2: B ni23 (4 reads); stage A-half1(t+1) ----
    ldB(sm + bB, wc, hi, lo, 2, b23);
    if (t + 1 < nt) STAGEH(Ag, (t + 1) * 64, aN, 1);
    __builtin_amdgcn_s_barrier();
    asm volatile("s_waitcnt lgkmcnt(0)" ::: "memory");
    __builtin_amdgcn_sched_barrier(0);
    __builtin_amdgcn_s_setprio(1);
    mm16(acc, 0, 2, a, b23);
    __builtin_amdgcn_s_setprio(0);
    __builtin_amdgcn_s_barrier();

    // ---- phase 3: A mi4-7 (8 reads); stage B-half0(t+2) into buf[c] ----
    ldA(sm + aB, wr, hi, lo, 4, a);
    if (t + 2 < nt) STAGEH(Bg, (t + 2) * 64, bB, 0);
    __builtin_amdgcn_s_barrier();
    asm volatile("s_waitcnt lgkmcnt(0)" ::: "memory");
    __builtin_amdgcn_sched_barrier(0);
    __builtin_amdgcn_s_setprio(1);
    mm16(acc, 4, 0, a, b01);
    __builtin_amdgcn_s_setprio(0);
    __builtin_amdgcn_s_barrier();

    // ---- phase 4: 0 reads; stage B-half1(t+2); boundary counted vmcnt ----
    if (t + 2 < nt) STAGEH(Bg, (t + 2) * 64, bB, 1);
    __builtin_amdgcn_s_barrier();
    __builtin_amdgcn_sched_barrier(0);
    __builtin_amdgcn_s_setprio(1);
    mm16(acc, 4, 2, a, b23);
    __builtin_amdgcn_s_setprio(0);
    // drain A(t+1)+B(t+1) (8 oldest); keep B(t+2) (4 loads) in flight
    if (t + 2 < nt)
      asm volatile("s_waitcnt vmcnt(4)" ::: "memory");
    else
      asm volatile("s_waitcnt vmcnt(0)" ::: "memory");
    __builtin_amdgcn_s_barrier();
  }

  // epilogue: C/D layout col=lane&15, row=(lane>>4)*4+r
  const int colb = n0 + wc * 64 + lo;
  const int rowb = m0 + wr * 128 + hi * 4;
#pragma unroll
  for (int ni = 0; ni < 4; ni++) {
    const float bv = bias[colb + ni * 16];
#pragma unroll
    for (int mi = 0; mi < 8; mi++) {
#pragma unroll
      for (int r = 0; r < 4; r++) {
        float v = acc[mi][ni][r] + bv;
        if (RELU) v = fmaxf(v, 0.0f);
        const size_t off = (size_t)(rowb + mi * 16 + r) * N + colb + ni * 16;
        if (WF32) Cf[off] = v;
        if (WB16) {
          bf16 tb = __float2bfloat16(v);
          Cb[off] = *(ushort*)&tb;
        }
      }
    }
  }
}

// ---------------------------------------------------------------------------
// 128²/64² bf16 MFMA GEMM (round-3 proven) — kept for GEMM2 (N=64) and the
// decoder hidden layer (K=64), where the 256² tile doesn't fit.
// ---------------------------------------------------------------------------
template <int BM, int BN, int WR, int WC, bool RELU, bool WF32, bool WB16>
__global__ __launch_bounds__(256, 3) void gemm_bt(
    const ushort* __restrict__ A, const ushort* __restrict__ B,
    const float* __restrict__ bias, float* __restrict__ Cf,
    ushort* __restrict__ Cb, int M, int N, int K) {
  constexpr int FM = (BM / WR) / 16;
  constexpr int FN = (BN / WC) / 16;
  __shared__ __align__(16) short sm[(BM + BN) * 64];

  const int tid = threadIdx.x;
  const int lane = tid & 63;
  const int w = tid >> 6;
  const int wr = w / WC, wc = w % WC;

  const int nwg = gridDim.x * gridDim.y;
  int bid = blockIdx.y * gridDim.x + blockIdx.x;
  if ((nwg & 7) == 0) bid = (bid & 7) * (nwg >> 3) + (bid >> 3);
  const int bx = bid % gridDim.x, by = bid / gridDim.x;
  const int m0 = by * BM, n0 = bx * BN;

  const ushort* Ag = A + (size_t)m0 * K;
  const ushort* Bg = B + (size_t)n0 * K;

  f32x4 acc[FM][FN] = {};

  for (int kt = 0; kt < K; kt += 64) {
#pragma unroll
    for (int j = 0; j < BM / 32; j++) {
      const int cb = j * 256 + w * 64;
      const int c = cb + lane;
      const int r = c >> 3;
      const int kc = (c & 7) ^ (r & 7);
      const ushort* src = Ag + (size_t)r * K + kt + kc * 8;
      const short* ld = sm + cb * 8;
      uint32_t m0v = __builtin_amdgcn_readfirstlane((uint32_t)(uintptr_t)ld);
      asm volatile("s_mov_b32 m0, %0\n\t"
                   "global_load_lds_dwordx4 %1, off\n\t"
                   :: "s"(m0v), "v"(src) : "memory");
    }
#pragma unroll
    for (int j = 0; j < BN / 32; j++) {
      const int cb = j * 256 + w * 64;
      const int c = cb + lane;
      const int r = c >> 3;
      const int kc = (c & 7) ^ (r & 7);
      const ushort* src = Bg + (size_t)r * K + kt + kc * 8;
      const short* ld = sm + (BM * 8 + cb) * 8;
      uint32_t m0v = __builtin_amdgcn_readfirstlane((uint32_t)(uintptr_t)ld);
      asm volatile("s_mov_b32 m0, %0\n\t"
                   "global_load_lds_dwordx4 %1, off\n\t"
                   :: "s"(m0v), "v"(src) : "memory");
    }
    asm volatile("s_waitcnt vmcnt(0)" ::: "memory");
    __syncthreads();

#pragma unroll
    for (int s = 0; s < 2; s++) {
      bf16x8 af[FM];
#pragma unroll
      for (int mi = 0; mi < FM; mi++) {
        const int p = wr * (BM / WR) + mi * 16 + (lane & 15);
        const int ch = (s * 4 + (lane >> 4)) ^ (p & 7);
        af[mi] = *(const bf16x8*)(sm + p * 64 + ch * 8);
      }
#pragma unroll
      for (int ni = 0; ni < FN; ni++) {
        const int q = wc * (BN / WC) + ni * 16 + (lane & 15);
        const int ch = (s * 4 + (lane >> 4)) ^ (q & 7);
        bf16x8 bfv = *(const bf16x8*)(sm + BM * 64 + q * 64 + ch * 8);
#pragma unroll
        for (int mi = 0; mi < FM; mi++)
          acc[mi][ni] = __builtin_amdgcn_mfma_f32_16x16x32_bf16(
              af[mi], bfv, acc[mi][ni], 0, 0, 0);
      }
    }
    __syncthreads();
  }

  const int colb = n0 + wc * (BN / WC) + (lane & 15);
  const int rowb = m0 + wr * (BM / WR) + ((lane >> 4) << 2);
#pragma unroll
  for (int ni = 0; ni < FN; ni++) {
    const float bv = bias[colb + ni * 16];
#pragma unroll
    for (int mi = 0; mi < FM; mi++) {
#pragma unroll
      for (int r = 0; r < 4; r++) {
        float v = acc[mi][ni][r] + bv;
        if (RELU) v = fmaxf(v, 0.0f);
        const size_t off = (size_t)(rowb + mi * 16 + r) * N + colb + ni * 16;
        if (WF32) Cf[off] = v;
        if (WB16) {
          bf16 t = __float2bfloat16(v);
          Cb[off] = *(ushort*)&t;
        }
      }
    }
  }
}

// ---------------------------------------------------------------------------
// f32 -> bf16 convert, 8 elems/thread, grid-stride
// ---------------------------------------------------------------------------
__global__ void cvt_bf16_kernel(const float* __restrict__ src,
                                ushort* __restrict__ dst, long n8) {
  long i = (long)blockIdx.x * blockDim.x + threadIdx.x;
  const long stride = (long)gridDim.x * blockDim.x;
  for (; i < n8; i += stride) {
    float4 v0 = ((const float4*)src)[i * 2];
    float4 v1 = ((const float4*)src)[i * 2 + 1];
    float a[8] = {v0.x, v0.y, v0.z, v0.w, v1.x, v1.y, v1.z, v1.w};
    uint h[8];
#pragma unroll
    for (int c = 0; c < 8; c++) {
      bf16 b = __float2bfloat16(a[c]);
      h[c] = *(ushort*)&b;
    }
    uint4 o;
    o.x = h[0] | (h[1] << 16);
    o.y = h[2] | (h[3] << 16);
    o.z = h[4] | (h[5] << 16);
    o.w = h[6] | (h[7] << 16);
    ((uint4*)dst)[i] = o;
  }
}

// ---------------------------------------------------------------------------
// Transposing convert: src (R x C f32) -> dst (C x R bf16)
// ---------------------------------------------------------------------------
__global__ __launch_bounds__(256) void tconv_kernel(
    const float* __restrict__ src, ushort* __restrict__ dst, int R, int C) {
  __shared__ float t[32][33];
  const int c0 = blockIdx.x * 32, r0 = blockIdx.y * 32;
  const int tx = threadIdx.x & 31, ty = threadIdx.x >> 5;
#pragma unroll
  for (int i = 0; i < 32; i += 8)
    t[ty + i][tx] = src[(size_t)(r0 + ty + i) * C + c0 + tx];
  __syncthreads();
#pragma unroll
  for (int i = 0; i < 32; i += 8) {
    bf16 b = __float2bfloat16(t[tx][ty + i]);
    dst[(size_t)(c0 + ty + i) * R + r0 + tx] = *(ushort*)&b;
  }
}

// ---------------------------------------------------------------------------
// Row squared-norm (rows of width 64)
// ---------------------------------------------------------------------------
__global__ void rownorm64_kernel(const float* __restrict__ v,
                                 float* __restrict__ out, int rows) {
  int r = blockIdx.x * blockDim.x + threadIdx.x;
  if (r >= rows) return;
  const float* p = v + (size_t)r * 64;
  float s = 0.0f;
#pragma unroll 8
  for (int k = 0; k < 64; k++) {
    float q = __fmul_rn(p[k], p[k]);
    s = __fadd_rn(s, q);
  }
  out[r] = s;
}

// ---------------------------------------------------------------------------
// VQ argmin via MFMA. d'_j = cn[j] - 2 * <z[r], c[j]>  (zn dropped: row-const)
// ---------------------------------------------------------------------------
#define AM_CHUNK 2048
__global__ __launch_bounds__(256) void vq_argmin_mfma(
    const ushort* __restrict__ z16, const ushort* __restrict__ cb16,
    const float* __restrict__ cn, float2* __restrict__ partials) {
  const int tid = threadIdx.x;
  const int lane = tid & 63;
  const int w = tid >> 6;
  const int r0 = blockIdx.x * 64 + w * 16;
  const int c0 = blockIdx.y * AM_CHUNK;

  const ushort* zrow =
      z16 + (size_t)(r0 + (lane & 15)) * 64 + ((lane >> 4) * 8);
  const bf16x8 a0 = *(const bf16x8*)zrow;
  const bf16x8 a1 = *(const bf16x8*)(zrow + 32);

  float best[4];
  int bidx[4];
#pragma unroll
  for (int r = 0; r < 4; r++) {
    best[r] = 3.402823466e38f;
    bidx[r] = 0;
  }

  for (int t = 0; t < AM_CHUNK / 16; t++) {
    const int j = c0 + t * 16 + (lane & 15);
    const ushort* crow = cb16 + (size_t)j * 64 + ((lane >> 4) * 8);
    const bf16x8 b0 = *(const bf16x8*)crow;
    const bf16x8 b1 = *(const bf16x8*)(crow + 32);
    f32x4 acc = {0.0f, 0.0f, 0.0f, 0.0f};
    acc = __builtin_amdgcn_mfma_f32_16x16x32_bf16(a0, b0, acc, 0, 0, 0);
    acc = __builtin_amdgcn_mfma_f32_16x16x32_bf16(a1, b1, acc, 0, 0, 0);
    const float cnv = cn[j];
#pragma unroll
    for (int r = 0; r < 4; r++) {
      const float d = fmaf(-2.0f, acc[r], cnv);
      if (d < best[r]) {
        best[r] = d;
        bidx[r] = j;
      }
    }
  }

#pragma unroll
  for (int m = 1; m < 16; m <<= 1) {
#pragma unroll
    for (int r = 0; r < 4; r++) {
      const float ov = __shfl_xor(best[r], m, 64);
      const int oi = __shfl_xor(bidx[r], m, 64);
      if (ov < best[r] || (ov == best[r] && oi < bidx[r])) {
        best[r] = ov;
        bidx[r] = oi;
      }
    }
  }
  if ((lane & 15) == 0) {
#pragma unroll
    for (int r = 0; r < 4; r++) {
      const int row = r0 + ((lane >> 4) << 2) + r;
      partials[(size_t)row * (NC / AM_CHUNK) + blockIdx.y] =
          make_float2(best[r], __int_as_float(bidx[r]));
    }
  }
}

__global__ void argmin_reduce_kernel(const float2* __restrict__ partials,
                                     int* __restrict__ idx) {
  const int row = blockIdx.x * 256 + threadIdx.x;
  float2 best = partials[(size_t)row * (NC / AM_CHUNK)];
#pragma unroll
  for (int c = 1; c < NC / AM_CHUNK; c++) {
    const float2 p = partials[(size_t)row * (NC / AM_CHUNK) + c];
    if (p.x < best.x) best = p;
  }
  idx[row] = __float_as_int(best.y);
}

// ---------------------------------------------------------------------------
// z output: out0[r] = z_e[r] + (codebook[idx[r]] - z_e[r]) in f32
// ---------------------------------------------------------------------------
__global__ void gather_z_kernel(const float* __restrict__ z_e,
                                const float* __restrict__ cb,
                                const int* __restrict__ idx,
                                float* __restrict__ out0) {
  int t = blockIdx.x * 256 + threadIdx.x;
  int row = t >> 4;
  int c4 = t & 15;
  int code = idx[row];
  float4 q = *reinterpret_cast<const float4*>(&cb[(size_t)code * 64 + c4 * 4]);
  float4 e = *reinterpret_cast<const float4*>(&z_e[(size_t)row * 64 + c4 * 4]);
  float4 o;
  o.x = __fadd_rn(e.x, __fsub_rn(q.x, e.x));
  o.y = __fadd_rn(e.y, __fsub_rn(q.y, e.y));
  o.z = __fadd_rn(e.z, __fsub_rn(q.z, e.z));
  o.w = __fadd_rn(e.w, __fsub_rn(q.w, e.w));
  *reinterpret_cast<float4*>(&out0[(size_t)row * 64 + c4 * 4]) = o;
}

__global__ void gather_recon_kernel(const float* __restrict__ table,
                                    const int* __restrict__ idx,
                                    float* __restrict__ out1) {
  int row = blockIdx.x >> 2;
  int q = blockIdx.x & 3;
  int c4 = q * 256 + threadIdx.x;
  int code = idx[row];
  float4 v = *reinterpret_cast<const float4*>(
      &table[(size_t)code * 4096 + (size_t)c4 * 4]);
  *reinterpret_cast<float4*>(&out1[(size_t)row * 4096 + (size_t)c4 * 4]) = v;
}

// ---------------------------------------------------------------------------
extern "C" void kernel_launch(void* const* d_in, const int* in_sizes, int n_in,
                              void* d_out, int out_size, void* d_ws,
                              size_t ws_size, hipStream_t stream) {
  const float* x   = (const float*)d_in[0];
  const float* W1  = (const float*)d_in[1];
  const float* b1  = (const float*)d_in[2];
  const float* W2  = (const float*)d_in[3];
  const float* b2  = (const float*)d_in[4];
  const float* cb  = (const float*)d_in[5];
  const float* dW1 = (const float*)d_in[6];
  const float* db1 = (const float*)d_in[7];
  const float* dW2 = (const float*)d_in[8];
  const float* db2 = (const float*)d_in[9];

  float* out0 = (float*)d_out;                      // z: 16384 x 64 (4 MB)
  char* o1b = (char*)d_out + (size_t)BROWS * BOT * 4;  // x_recon region 256 MB
  float* out1 = (float*)o1b;

  // out1-region scratch (all dead before gather_recon overwrites out1):
  ushort* x16   = (ushort*)(o1b);                    // [0,128M)   a..GEMM1
  ushort* W1t   = (ushort*)(o1b + 128 * MB);         // [128,144M) ..GEMM1
  ushort* h16   = (ushort*)(o1b + 144 * MB);         // [144,208M) GEMM1..GEMM2
  float*  z_e   = (float*)(o1b + 64 * MB);           // [64,68M)   GEMM2..gather
  ushort* z16   = (ushort*)(o1b + 68 * MB);          // [68,70M)   GEMM2..argmin
  ushort* cb16  = (ushort*)(o1b + 70 * MB);          // [70,71M)   ..dec-hidden
  float*  cn    = (float*)(o1b + 71 * MB);           // 32 KB      ..argmin
  float2* parts = (float2*)(o1b + 71 * MB + 524288); // 512 KB     argmin..red
  ushort* W2t   = (ushort*)(o1b + 72 * MB);          // 256 KB     ..GEMM2
  ushort* dW1t  = (ushort*)(o1b + 73 * MB);          // 256 KB     ..dec-hidden
  ushort* ht16  = (ushort*)(o1b);                    // [0,32M)    dec..table
  ushort* dW2t  = (ushort*)(o1b + 32 * MB);          // [32,64M)   ..table

  // workspace: table + idx only (high-water ~128.1 MB)
  char* wsb = (char*)d_ws;
  float* table = (float*)wsb;                        // [0,128M)   table..gather
  int*   idxb  = (int*)(wsb + 128 * MB);             // 64 KB      red..gathers

  dim3 blk(256);

  // a. x -> bf16
  cvt_bf16_kernel<<<dim3(2048), blk, 0, stream>>>(x, x16,
                                                  (long)BROWS * INDIM / 8);
  // b. W1^T -> bf16 (2048 x 4096)
  tconv_kernel<<<dim3(HID / 32, INDIM / 32), blk, 0, stream>>>(W1, W1t, INDIM,
                                                               HID);
  // c. GEMM1: h = relu(x @ W1 + b1), bf16 out   M=16384 N=2048 K=4096
  gemm256<true, false, true>
      <<<dim3(HID / 256, BROWS / 256), dim3(512), 0, stream>>>(
          x16, W1t, b1, nullptr, h16, BROWS, HID, INDIM);
  // d. W2^T -> bf16 (64 x 2048)
  tconv_kernel<<<dim3(BOT / 32, HID / 32), blk, 0, stream>>>(W2, W2t, HID,
                                                             BOT);
  // e. GEMM2: z_e = h @ W2 + b2, f32 + bf16 out  M=16384 N=64 K=2048
  gemm_bt<64, 64, 2, 2, false, true, true>
      <<<dim3(1, BROWS / 64), blk, 0, stream>>>(h16, W2t, b2, z_e, z16, BROWS,
                                                BOT, HID);
  // f. codebook -> bf16
  cvt_bf16_kernel<<<dim3(256), blk, 0, stream>>>(cb, cb16, (long)NC * BOT / 8);
  // g. cn = ||c||^2
  rownorm64_kernel<<<dim3(NC / 256), blk, 0, stream>>>(cb, cn, NC);
  // h. argmin (MFMA, 4 code chunks)
  vq_argmin_mfma<<<dim3(BROWS / 64, NC / AM_CHUNK), blk, 0, stream>>>(
      z16, cb16, cn, parts);
  // i. reduce chunks
  argmin_reduce_kernel<<<dim3(BROWS / 256), blk, 0, stream>>>(parts, idxb);
  // j. dW1^T -> bf16 (2048 x 64)
  tconv_kernel<<<dim3(HID / 32, BOT / 32), blk, 0, stream>>>(dW1, dW1t, BOT,
                                                             HID);
  // k. decoder hidden: ht = relu(cb @ dW1 + db1), bf16 out M=8192 N=2048 K=64
  gemm_bt<128, 128, 2, 2, true, false, true>
      <<<dim3(HID / 128, NC / 128), blk, 0, stream>>>(cb16, dW1t, db1, nullptr,
                                                      ht16, NC, HID, BOT);
  // l. dW2^T -> bf16 (4096 x 2048)
  tconv_kernel<<<dim3(INDIM / 32, HID / 32), blk, 0, stream>>>(dW2, dW2t, HID,
                                                               INDIM);
  // m. table = ht @ dW2 + db2, f32 out  M=8192 N=4096 K=2048
  gemm256<false, true, false>
      <<<dim3(INDIM / 256, NC / 256), dim3(512), 0, stream>>>(
          ht16, dW2t, db2, table, nullptr, NC, INDIM, HID);
  // n. z output
  gather_z_kernel<<<dim3(BROWS * 16 / 256), blk, 0, stream>>>(z_e, cb, idxb,
                                                              out0);
  // o. x_recon output
  gather_recon_kernel<<<dim3(BROWS * 4), blk, 0, stream>>>(table, idxb, out1);
}